// Round 2
// baseline (896.596 us; speedup 1.0000x reference)
//
#include <hip/hip_runtime.h>
#include <hip/hip_bf16.h>
#include <cstdint>
#include <cstddef>

#define M_ 4096
#define K_ 7168
#define N_ 18432

typedef __attribute__((ext_vector_type(4))) int i32x4;

#define AS1 __attribute__((address_space(1)))
#define AS3 __attribute__((address_space(3)))

__device__ __forceinline__ void gld_lds16(void* lds, const void* g) {
  // async global->LDS, 16B per lane; LDS dest = wave-uniform base + lane*16
  __builtin_amdgcn_global_load_lds((const AS1 void*)g, (AS3 void*)lds, 16, 0, 0);
}

// ---------------- prepass 1: per-row dynamic quantization of x ----------------
__global__ __launch_bounds__(256) void quant_x_kernel(const float* __restrict__ x,
                                                      signed char* __restrict__ xq,
                                                      float* __restrict__ sx) {
  const int m = blockIdx.x;
  const float4* row4 = (const float4*)(x + (size_t)m * K_);
  float mx = 0.f;
  for (int i = threadIdx.x; i < K_ / 4; i += 256) {
    float4 v = row4[i];
    mx = fmaxf(mx, fmaxf(fmaxf(fabsf(v.x), fabsf(v.y)), fmaxf(fabsf(v.z), fabsf(v.w))));
  }
#pragma unroll
  for (int d = 1; d < 64; d <<= 1) mx = fmaxf(mx, __shfl_xor(mx, d));
  __shared__ float wred[4];
  if ((threadIdx.x & 63) == 0) wred[threadIdx.x >> 6] = mx;
  __syncthreads();
  mx = fmaxf(fmaxf(wred[0], wred[1]), fmaxf(wred[2], wred[3]));
  const float inv = mx > 0.f ? 127.f / mx : 0.f;
  if (threadIdx.x == 0) sx[m] = mx / 127.f;
  char4* q4 = (char4*)(xq + (size_t)m * K_);
  for (int i = threadIdx.x; i < K_ / 4; i += 256) {
    float4 v = row4[i];
    char4 c;
    c.x = (signed char)__float2int_rn(v.x * inv);
    c.y = (signed char)__float2int_rn(v.y * inv);
    c.z = (signed char)__float2int_rn(v.z * inv);
    c.w = (signed char)__float2int_rn(v.w * inv);
    q4[i] = c;
  }
}

// ---- prepass 2: W int32 [K,N] -> Wt int8 [N,K] (convert + transpose) ----
__global__ __launch_bounds__(256) void transpose_w_kernel(const int* __restrict__ W,
                                                          signed char* __restrict__ Wt) {
  __shared__ __align__(16) signed char t[64][80];  // [n_local][k_local], 80 keeps int4 aligned
  const int k0 = blockIdx.x * 64;
  const int n0 = blockIdx.y * 64;
  const int r = threadIdx.x >> 4;          // 0..15
  const int c4 = (threadIdx.x & 15) * 4;   // 0,4,...,60
#pragma unroll
  for (int rr = 0; rr < 4; ++rr) {
    const int row = rr * 16 + r;
    int4 v = *(const int4*)(W + (size_t)(k0 + row) * N_ + n0 + c4);  // coalesced along N
    t[c4 + 0][row] = (signed char)v.x;
    t[c4 + 1][row] = (signed char)v.y;
    t[c4 + 2][row] = (signed char)v.z;
    t[c4 + 3][row] = (signed char)v.w;
  }
  __syncthreads();
  const int nr = threadIdx.x >> 2;         // 0..63
  const int cb = (threadIdx.x & 3) * 16;   // 0,16,32,48
  int4 o = *(const int4*)&t[nr][cb];
  *(int4*)(Wt + (size_t)(n0 + nr) * K_ + k0 + cb) = o;  // coalesced along K
}

// ---------------- main GEMM: int8 MFMA, m97-structure (128x128 tile, BK=64) ----------------
__global__ __launch_bounds__(256) void gemm_i8_kernel(const signed char* __restrict__ Aq,  // [M,K]
                                                      const signed char* __restrict__ Bt,  // [N,K]
                                                      const float* __restrict__ sx,        // [M]
                                                      const float* __restrict__ scale,     // [N]
                                                      float* __restrict__ C) {             // [M,N]
  __shared__ __align__(16) signed char As[8192];  // [128 rows][64 k] int8
  __shared__ __align__(16) signed char Bs[8192];  // [128 n-rows][64 k] int8

  const int NBN = N_ / 128;              // 144
  const int per = (M_ / 128) * NBN / 8;  // 576 (nwg % 8 == 0 -> bijective)
  const int bid = blockIdx.x;
  const int swz = (bid & 7) * per + (bid >> 3);  // XCD-aware swizzle
  const int bm = swz / NBN;
  const int bn = swz % NBN;
  const int m0 = bm * 128;
  const int n0 = bn * 128;

  const int tid = threadIdx.x;
  const int wid = tid >> 6;
  const int lane = tid & 63;
  const int wrow = wid >> 1;  // 0..1
  const int wcol = wid & 1;   // 0..1

  const int sr = tid >> 2;           // tile row 0..63
  const int sc = (tid & 3) << 4;     // k-byte offset 0,16,32,48
  const signed char* a_src0 = Aq + (size_t)(m0 + sr) * K_ + sc;
  const signed char* a_src1 = a_src0 + (size_t)64 * K_;
  const signed char* b_src0 = Bt + (size_t)(n0 + sr) * K_ + sc;
  const signed char* b_src1 = b_src0 + (size_t)64 * K_;
  signed char* a_dst0 = As + wid * 1024;          // wave-uniform LDS bases
  signed char* a_dst1 = As + 4096 + wid * 1024;
  signed char* b_dst0 = Bs + wid * 1024;
  signed char* b_dst1 = Bs + 4096 + wid * 1024;

  const int fr = lane & 15;   // fragment row (A: m, B: n)
  const int ko = lane >> 4;   // k-chunk quarter
  const int a_off = (wrow * 64 + fr) * 64 + ko * 16;
  const int b_off = (wcol * 64 + fr) * 64 + ko * 16;

  i32x4 acc[4][4] = {};

  for (int k = 0; k < K_; k += 64) {
    gld_lds16(a_dst0, a_src0 + k);
    gld_lds16(a_dst1, a_src1 + k);
    gld_lds16(b_dst0, b_src0 + k);
    gld_lds16(b_dst1, b_src1 + k);
    __syncthreads();  // compiler drains vmcnt before s_barrier

    i32x4 av[4], bv[4];
#pragma unroll
    for (int i = 0; i < 4; ++i) av[i] = *(const i32x4*)(As + a_off + i * 1024);
#pragma unroll
    for (int j = 0; j < 4; ++j) bv[j] = *(const i32x4*)(Bs + b_off + j * 1024);
#pragma unroll
    for (int i = 0; i < 4; ++i)
#pragma unroll
      for (int j = 0; j < 4; ++j)
        acc[i][j] = __builtin_amdgcn_mfma_i32_16x16x64_i8(av[i], bv[j], acc[i][j], 0, 0, 0);
    __syncthreads();
  }

  // epilogue: y = i32acc * sx[m] * scale[n]
  const int mb = m0 + wrow * 64;
  const int nb = n0 + wcol * 64;
  const int col = lane & 15;
  const int rq = (lane >> 4) * 4;  // C/D: col = lane&15, row = (lane>>4)*4 + reg
  float scl[4];
#pragma unroll
  for (int j = 0; j < 4; ++j) scl[j] = scale[nb + j * 16 + col];
#pragma unroll
  for (int i = 0; i < 4; ++i) {
#pragma unroll
    for (int r = 0; r < 4; ++r) {
      const int m = mb + i * 16 + rq + r;
      const float s = sx[m];
      float* out = C + (size_t)m * N_ + nb + col;
#pragma unroll
      for (int j = 0; j < 4; ++j) out[j * 16] = (float)acc[i][j][r] * s * scl[j];
    }
  }
}

// ---------------- fallback (only if ws_size too small): tiled fp32 vector GEMM ----------------
__global__ __launch_bounds__(256) void fb_gemm_kernel(const float* __restrict__ X,
                                                      const int* __restrict__ W,
                                                      const float* __restrict__ scale,
                                                      float* __restrict__ Y) {
  __shared__ float xs[16][65];
  __shared__ float ws_[16][65];
  const int bn = blockIdx.x * 64;
  const int bm = blockIdx.y * 64;
  const int tx = threadIdx.x & 15;
  const int ty = threadIdx.x >> 4;
  float acc[4][4] = {};
  for (int k0 = 0; k0 < K_; k0 += 16) {
    for (int i = threadIdx.x; i < 64 * 16; i += 256) {
      int r = i >> 4, c = i & 15;
      xs[c][r] = X[(size_t)(bm + r) * K_ + k0 + c];
    }
    for (int i = threadIdx.x; i < 16 * 64; i += 256) {
      int r = i >> 6, c = i & 63;
      ws_[r][c] = (float)W[(size_t)(k0 + r) * N_ + bn + c];
    }
    __syncthreads();
#pragma unroll
    for (int kk = 0; kk < 16; ++kk) {
      float a[4], b[4];
#pragma unroll
      for (int i = 0; i < 4; ++i) a[i] = xs[kk][ty * 4 + i];
#pragma unroll
      for (int j = 0; j < 4; ++j) b[j] = ws_[kk][tx * 4 + j];
#pragma unroll
      for (int i = 0; i < 4; ++i)
#pragma unroll
        for (int j = 0; j < 4; ++j) acc[i][j] += a[i] * b[j];
    }
    __syncthreads();
  }
#pragma unroll
  for (int i = 0; i < 4; ++i)
#pragma unroll
    for (int j = 0; j < 4; ++j)
      Y[(size_t)(bm + ty * 4 + i) * N_ + bn + tx * 4 + j] = acc[i][j] * scale[bn + tx * 4 + j];
}

extern "C" void kernel_launch(void* const* d_in, const int* in_sizes, int n_in,
                              void* d_out, int out_size, void* d_ws, size_t ws_size,
                              hipStream_t stream) {
  const float* x = (const float*)d_in[0];
  const int* w = (const int*)d_in[1];  // harness materializes int8 weights as int32
  const float* scale = (const float*)d_in[2];
  float* y = (float*)d_out;

  const size_t xq_bytes = (size_t)M_ * K_;        // 29,360,128
  const size_t sx_off = xq_bytes;
  const size_t wt_off = sx_off + (size_t)M_ * 4;  // 29,376,512 (16-aligned)
  const size_t need = wt_off + (size_t)N_ * K_;   // ~161.5 MB

  if (ws_size >= need) {
    signed char* xq = (signed char*)d_ws;
    float* sx = (float*)((char*)d_ws + sx_off);
    signed char* wt = (signed char*)((char*)d_ws + wt_off);
    hipLaunchKernelGGL(quant_x_kernel, dim3(M_), dim3(256), 0, stream, x, xq, sx);
    hipLaunchKernelGGL(transpose_w_kernel, dim3(K_ / 64, N_ / 64), dim3(256), 0, stream, w, wt);
    hipLaunchKernelGGL(gemm_i8_kernel, dim3((M_ / 128) * (N_ / 128)), dim3(256), 0, stream,
                       xq, wt, sx, scale, y);
  } else {
    // correctness safety net (slow): pure fp32 tiled GEMM, no workspace
    hipLaunchKernelGGL(fb_gemm_kernel, dim3(N_ / 64, M_ / 64), dim3(256), 0, stream,
                       x, w, scale, y);
  }
}

// Round 3
// 723.485 us; speedup vs baseline: 1.2393x; 1.2393x over previous
//
#include <hip/hip_runtime.h>
#include <hip/hip_bf16.h>
#include <cstdint>
#include <cstddef>

#define M_ 4096
#define K_ 7168
#define N_ 18432
#define NT 56     // K-tiles of BK=128
#define ITERS 28  // 2 K-tiles per iteration

typedef __attribute__((ext_vector_type(4))) int i32x4;

#define AS1 __attribute__((address_space(1)))
#define AS3 __attribute__((address_space(3)))

__device__ __forceinline__ void gld_lds16(void* lds, const void* g) {
  __builtin_amdgcn_global_load_lds((const AS1 void*)g, (AS3 void*)lds, 16, 0, 0);
}

// ---------------- prepass 1: per-row dynamic quantization of x ----------------
__global__ __launch_bounds__(256) void quant_x_kernel(const float* __restrict__ x,
                                                      signed char* __restrict__ xq,
                                                      float* __restrict__ sx) {
  const int m = blockIdx.x;
  const float4* row4 = (const float4*)(x + (size_t)m * K_);
  float mx = 0.f;
  for (int i = threadIdx.x; i < K_ / 4; i += 256) {
    float4 v = row4[i];
    mx = fmaxf(mx, fmaxf(fmaxf(fabsf(v.x), fabsf(v.y)), fmaxf(fabsf(v.z), fabsf(v.w))));
  }
#pragma unroll
  for (int d = 1; d < 64; d <<= 1) mx = fmaxf(mx, __shfl_xor(mx, d));
  __shared__ float wred[4];
  if ((threadIdx.x & 63) == 0) wred[threadIdx.x >> 6] = mx;
  __syncthreads();
  mx = fmaxf(fmaxf(wred[0], wred[1]), fmaxf(wred[2], wred[3]));
  const float inv = mx > 0.f ? 127.f / mx : 0.f;
  if (threadIdx.x == 0) sx[m] = mx / 127.f;
  char4* q4 = (char4*)(xq + (size_t)m * K_);
  for (int i = threadIdx.x; i < K_ / 4; i += 256) {
    float4 v = row4[i];
    char4 c;
    c.x = (signed char)__float2int_rn(v.x * inv);
    c.y = (signed char)__float2int_rn(v.y * inv);
    c.z = (signed char)__float2int_rn(v.z * inv);
    c.w = (signed char)__float2int_rn(v.w * inv);
    q4[i] = c;
  }
}

// ---- prepass 2: W int32 [K,N] -> Wt int8 [N,K] (convert + transpose) ----
__global__ __launch_bounds__(256) void transpose_w_kernel(const int* __restrict__ W,
                                                          signed char* __restrict__ Wt) {
  __shared__ __align__(16) signed char t[64][80];
  const int k0 = blockIdx.x * 64;
  const int n0 = blockIdx.y * 64;
  const int r = threadIdx.x >> 4;
  const int c4 = (threadIdx.x & 15) * 4;
#pragma unroll
  for (int rr = 0; rr < 4; ++rr) {
    const int row = rr * 16 + r;
    int4 v = *(const int4*)(W + (size_t)(k0 + row) * N_ + n0 + c4);
    t[c4 + 0][row] = (signed char)v.x;
    t[c4 + 1][row] = (signed char)v.y;
    t[c4 + 2][row] = (signed char)v.z;
    t[c4 + 3][row] = (signed char)v.w;
  }
  __syncthreads();
  const int nr = threadIdx.x >> 2;
  const int cb = (threadIdx.x & 3) * 16;
  int4 o = *(const int4*)&t[nr][cb];
  *(int4*)(Wt + (size_t)(n0 + nr) * K_ + k0 + cb) = o;
}

// ============ main GEMM: 256x256 tile, BK=128, 8-wave, 8-phase counted-vmcnt ============
// LDS: A region [0,65536), B region [65536,131072).
//   addr(op, buf, ks, row, physslot) = opbase + buf*32768 + ks*16384 + row*64 + physslot*16
// Swizzle (T2): physslot = slot ^ ((row>>1)&3). Applied on gld_lds SOURCE (inverse) + ds_read.
__global__ __launch_bounds__(512, 2) void gemm_i8_kernel(const signed char* __restrict__ Aq,
                                                         const signed char* __restrict__ Bt,
                                                         const float* __restrict__ sx,
                                                         const float* __restrict__ scale,
                                                         float* __restrict__ C) {
  __shared__ __align__(16) signed char lds[131072];

  const int NBN = 72;   // N/256
  const int per = 144;  // 1152/8 (bijective XCD swizzle)
  const int bid = blockIdx.x;
  const int swz = (bid & 7) * per + (bid >> 3);
  const int m0 = (swz / NBN) * 256;
  const int n0 = (swz % NBN) * 256;

  const int tid = threadIdx.x;
  const int w = tid >> 6;      // wave 0..7
  const int lane = tid & 63;
  const int wr = w >> 2;       // 0..1 (M)
  const int wc = w & 3;        // 0..3 (N)

  // ds_read fragment addressing: row = base + fr, slot q; phys = q ^ ((fr>>1)&3)
  const int fr = lane & 15;
  const int q = lane >> 4;
  const int sl = ((q ^ ((fr >> 1) & 3)) << 4);

  // staging per-lane: block-linear L = j*8192 + w*1024 + lane*16 ->
  //   pr = j*128 + w*16 + (lane>>2), physslot = lane&3,
  //   logical slot ls = (lane&3) ^ ((pr>>1)&3) = (lane&3) ^ ((lane>>3)&3)
  const int ls16 = (((lane & 3) ^ ((lane >> 3) & 3)) << 4);
  const int pr0 = w * 16 + (lane >> 2);
  const unsigned offA0 = (unsigned)(m0 + pr0) * K_ + ls16;
  const unsigned offA1 = (unsigned)(m0 + 128 + pr0) * K_ + ls16;
  const unsigned offB0 = (unsigned)(n0 + pr0) * K_ + ls16;
  const unsigned offB1 = (unsigned)(n0 + 128 + pr0) * K_ + ls16;

#define STAGE_A(T, KS) do {                                                        \
    const int tc_ = (T) < NT ? (T) : NT - 1;                                       \
    signed char* d_ = lds + (((T) & 1) * 32768 + (KS) * 16384 + w * 1024);         \
    gld_lds16(d_, Aq + (size_t)offA0 + tc_ * 128 + (KS) * 64);                     \
    gld_lds16(d_ + 8192, Aq + (size_t)offA1 + tc_ * 128 + (KS) * 64);              \
  } while (0)
#define STAGE_B(T, KS) do {                                                        \
    const int tc_ = (T) < NT ? (T) : NT - 1;                                       \
    signed char* d_ = lds + (65536 + ((T) & 1) * 32768 + (KS) * 16384 + w * 1024); \
    gld_lds16(d_, Bt + (size_t)offB0 + tc_ * 128 + (KS) * 64);                     \
    gld_lds16(d_ + 8192, Bt + (size_t)offB1 + tc_ * 128 + (KS) * 64);              \
  } while (0)
#define LDA(BUF, KS, MH) do {                                                      \
    const signed char* ab = lds + ((BUF) * 32768 + (KS) * 16384);                  \
    _Pragma("unroll") for (int i_ = 0; i_ < 4; ++i_)                               \
      aq[i_] = *(const i32x4*)(ab + (wr * 128 + ((MH) * 4 + i_) * 16 + fr) * 64 + sl); \
  } while (0)
#define LDB(BUF, KS) do {                                                          \
    const signed char* bb = lds + (65536 + (BUF) * 32768 + (KS) * 16384);          \
    _Pragma("unroll") for (int n_ = 0; n_ < 4; ++n_)                               \
      bq[n_] = *(const i32x4*)(bb + (wc * 64 + n_ * 16 + fr) * 64 + sl);           \
  } while (0)
#define MFMA16(MH) do {                                                            \
    __builtin_amdgcn_s_setprio(1);                                                 \
    _Pragma("unroll") for (int i_ = 0; i_ < 4; ++i_)                               \
    _Pragma("unroll") for (int n_ = 0; n_ < 4; ++n_)                               \
      acc[(MH) * 4 + i_][n_] = __builtin_amdgcn_mfma_i32_16x16x64_i8(              \
          aq[i_], bq[n_], acc[(MH) * 4 + i_][n_], 0, 0, 0);                        \
    __builtin_amdgcn_s_setprio(0);                                                 \
  } while (0)
#define FENCE asm volatile("" ::: "memory")
#define BAR do { FENCE; __builtin_amdgcn_s_barrier(); FENCE; } while (0)
#define LGKM0 asm volatile("s_waitcnt lgkmcnt(0)")
#define VM6 asm volatile("s_waitcnt vmcnt(6)")

  i32x4 acc[8][4] = {};
  i32x4 aq[4], bq[4];

  // Prologue: tile0 {B0,A0,B1,A1}, tile1 {B0,A0,B1}; drain tile0, keep 3 half-tiles in flight.
  STAGE_B(0, 0); STAGE_A(0, 0); STAGE_B(0, 1); STAGE_A(0, 1);
  STAGE_B(1, 0); STAGE_A(1, 0); STAGE_B(1, 1);
  VM6;
  BAR;

  for (int it = 0; it < ITERS; ++it) {
    const int u = 2 * it;  // tile u -> buf0, tile u+1 -> buf1 (u even)
    // ---- tile u (buf0) ----
    // ph1: ks0, m0-3   | stage (u+1):A1 -> buf1 (A-ks1 last read prev ph7/ph8)
    LDB(0, 0); LDA(0, 0, 0);
    STAGE_A(u + 1, 1);
    BAR; LGKM0;
    MFMA16(0);
    BAR;
    // ph2: ks0, m4-7   | stage (u+2):B0 -> buf0 (B-ks0 read in ph1)
    LDA(0, 0, 1);
    STAGE_B(u + 2, 0);
    BAR; LGKM0;
    MFMA16(1);
    BAR;
    // ph3: ks1, m0-3   | stage (u+2):A0 -> buf0 (A-ks0 read in ph1-2)
    LDB(0, 1); LDA(0, 1, 0);
    STAGE_A(u + 2, 0);
    BAR; LGKM0;
    MFMA16(0);
    BAR;
    // ph4: ks1, m4-7   | stage (u+2):B1 -> buf0 (B-ks1 read in ph3) | boundary vmcnt
    LDA(0, 1, 1);
    STAGE_B(u + 2, 1);
    BAR; LGKM0;
    MFMA16(1);
    VM6;   // drains tile u+1 fully (FIFO: leaves u+2:{B0,A0,B1} in flight)
    BAR;
    // ---- tile u+1 (buf1) ----
    // ph5: ks0, m0-3   | stage (u+2):A1 -> buf0 (A-ks1 read in ph3-4)
    LDB(1, 0); LDA(1, 0, 0);
    STAGE_A(u + 2, 1);
    BAR; LGKM0;
    MFMA16(0);
    BAR;
    // ph6: ks0, m4-7   | stage (u+3):B0 -> buf1 (B-ks0 read in ph5)
    LDA(1, 0, 1);
    STAGE_B(u + 3, 0);
    BAR; LGKM0;
    MFMA16(1);
    BAR;
    // ph7: ks1, m0-3   | stage (u+3):A0 -> buf1 (A-ks0 read in ph5-6)
    LDB(1, 1); LDA(1, 1, 0);
    STAGE_A(u + 3, 0);
    BAR; LGKM0;
    MFMA16(0);
    BAR;
    // ph8: ks1, m4-7   | stage (u+3):B1 -> buf1 (B-ks1 read in ph7) | boundary vmcnt
    LDA(1, 1, 1);
    STAGE_B(u + 3, 1);
    BAR; LGKM0;
    MFMA16(1);
    VM6;   // drains tile u+2 fully
    BAR;
  }

  // epilogue: y = i32acc * sx[m] * scale[n]; C/D: col=lane&15, row=(lane>>4)*4+reg
  const int mb = m0 + wr * 128;
  const int nb = n0 + wc * 64;
  const int col = lane & 15;
  const int rq = (lane >> 4) * 4;
  float scl[4];
#pragma unroll
  for (int n = 0; n < 4; ++n) scl[n] = scale[nb + n * 16 + col];
#pragma unroll
  for (int m = 0; m < 8; ++m) {
#pragma unroll
    for (int r = 0; r < 4; ++r) {
      const int row = mb + m * 16 + rq + r;
      const float s = sx[row];
      float* out = C + (size_t)row * N_ + nb + col;
#pragma unroll
      for (int n = 0; n < 4; ++n) out[n * 16] = (float)acc[m][n][r] * s * scl[n];
    }
  }
#undef STAGE_A
#undef STAGE_B
#undef LDA
#undef LDB
#undef MFMA16
#undef FENCE
#undef BAR
#undef LGKM0
#undef VM6
}

// ---------------- fallback (only if ws_size too small): tiled fp32 vector GEMM ----------------
__global__ __launch_bounds__(256) void fb_gemm_kernel(const float* __restrict__ X,
                                                      const int* __restrict__ W,
                                                      const float* __restrict__ scale,
                                                      float* __restrict__ Y) {
  __shared__ float xs[16][65];
  __shared__ float ws_[16][65];
  const int bn = blockIdx.x * 64;
  const int bm = blockIdx.y * 64;
  const int tx = threadIdx.x & 15;
  const int ty = threadIdx.x >> 4;
  float acc[4][4] = {};
  for (int k0 = 0; k0 < K_; k0 += 16) {
    for (int i = threadIdx.x; i < 64 * 16; i += 256) {
      int r = i >> 4, c = i & 15;
      xs[c][r] = X[(size_t)(bm + r) * K_ + k0 + c];
    }
    for (int i = threadIdx.x; i < 16 * 64; i += 256) {
      int r = i >> 6, c = i & 63;
      ws_[r][c] = (float)W[(size_t)(k0 + r) * N_ + bn + c];
    }
    __syncthreads();
#pragma unroll
    for (int kk = 0; kk < 16; ++kk) {
      float a[4], b[4];
#pragma unroll
      for (int i = 0; i < 4; ++i) a[i] = xs[kk][ty * 4 + i];
#pragma unroll
      for (int j = 0; j < 4; ++j) b[j] = ws_[kk][tx * 4 + j];
#pragma unroll
      for (int i = 0; i < 4; ++i)
#pragma unroll
        for (int j = 0; j < 4; ++j) acc[i][j] += a[i] * b[j];
    }
    __syncthreads();
  }
#pragma unroll
  for (int i = 0; i < 4; ++i)
#pragma unroll
    for (int j = 0; j < 4; ++j)
      Y[(size_t)(bm + ty * 4 + i) * N_ + bn + tx * 4 + j] = acc[i][j] * scale[bn + tx * 4 + j];
}

extern "C" void kernel_launch(void* const* d_in, const int* in_sizes, int n_in,
                              void* d_out, int out_size, void* d_ws, size_t ws_size,
                              hipStream_t stream) {
  const float* x = (const float*)d_in[0];
  const int* w = (const int*)d_in[1];  // harness materializes int8 weights as int32
  const float* scale = (const float*)d_in[2];
  float* y = (float*)d_out;

  const size_t xq_bytes = (size_t)M_ * K_;
  const size_t sx_off = xq_bytes;
  const size_t wt_off = sx_off + (size_t)M_ * 4;
  const size_t need = wt_off + (size_t)N_ * K_;  // ~161.5 MB

  if (ws_size >= need) {
    signed char* xq = (signed char*)d_ws;
    float* sx = (float*)((char*)d_ws + sx_off);
    signed char* wt = (signed char*)((char*)d_ws + wt_off);
    hipLaunchKernelGGL(quant_x_kernel, dim3(M_), dim3(256), 0, stream, x, xq, sx);
    hipLaunchKernelGGL(transpose_w_kernel, dim3(K_ / 64, N_ / 64), dim3(256), 0, stream, w, wt);
    hipLaunchKernelGGL(gemm_i8_kernel, dim3((M_ / 256) * (N_ / 256)), dim3(512), 0, stream,
                       xq, wt, sx, scale, y);
  } else {
    hipLaunchKernelGGL(fb_gemm_kernel, dim3(N_ / 64, M_ / 64), dim3(256), 0, stream,
                       x, w, scale, y);
  }
}